// Round 8
// baseline (356.165 us; speedup 1.0000x reference)
//
#include <hip/hip_runtime.h>
#include <hip/hip_bf16.h>

typedef unsigned short u16;
typedef unsigned int u32;
typedef __bf16 bf16x8 __attribute__((ext_vector_type(8)));
typedef __bf16 bf16x4 __attribute__((ext_vector_type(4)));
typedef float f32x4 __attribute__((ext_vector_type(4)));

#define MFMA16(a, b, c) __builtin_amdgcn_mfma_f32_16x16x32_bf16((a), (b), (c), 0, 0, 0)

// async global->LDS, 16B per lane, wave-uniform LDS base (HW: base + lane*16)
#define GLOAD_LDS16(gp, lp)                                        \
    __builtin_amdgcn_global_load_lds(                              \
        (const __attribute__((address_space(1))) void*)(gp),       \
        (__attribute__((address_space(3))) void*)(lp), 16, 0, 0)

// round-to-nearest-even f32 -> bf16 bits
static __device__ __forceinline__ u32 f2bfbits(float f) {
    union { float f; u32 u; } c; c.f = f;
    return (c.u + 0x7FFFu + ((c.u >> 16) & 1u)) >> 16;
}
// exact for small integers (|v| <= 255): low 16 mantissa bits are zero
static __device__ __forceinline__ u32 f2bfbits_exact(float f) {
    union { float f; u32 u; } c; c.f = f;
    return c.u >> 16;
}
// packed RNE f32x2 -> bf16x2
static __device__ __forceinline__ u32 pack_bf16x2(float lo, float hi) {
    float2 v; v.x = lo; v.y = hi;
    union { __hip_bfloat162 h; u32 u; } c;
    c.h = __float22bfloat162_rn(v);
    return c.u;  // low 16 = lo, high 16 = hi
}

// guaranteed single-instruction rotate: v_alignbit_b32(x,x,32-r) == rotl(x,r)
static __device__ __forceinline__ u32 rotl_ab(u32 x, int r) {
    return __builtin_amdgcn_alignbit(x, x, 32 - r);
}

// v_exp_f32 computes 2^x. Inline asm so we skip __expf's ln2 multiply (the
// constants upstream are pre-scaled by log2e). s_nop 1 covers the VALU-trans
// use hazard, which the scheduler cannot see inside opaque asm.
static __device__ __forceinline__ float exp2_fast(float x) {
    float r;
    asm("v_exp_f32 %0, %1\n\ts_nop 1" : "=v"(r) : "v"(x));
    return r;
}

// ---------------- batched JAX threefry2x32, key (0,42), 8 draws in lockstep.
// Partitionable mode (HW-verified): counter=(0,idx), bits=x0^x1.
// tk = base_idx + 42 (key pre-added); draw d uses idx offset {0,1,2,3,16,17,18,19}.
// Harness-verified bitstream (R0..R7 absmax identical). R5 scalar-tail form.
static __device__ __forceinline__ void noise_pu8(u32 tk, float* __restrict__ pu) {
    const u32 K1 = 42u, K2 = 0x1BD11BF0u;  // 0x1BD11BDA ^ 42
    u32 x0[8], x1[8];
#pragma unroll
    for (int d = 0; d < 8; d++) {
        u32 a = tk + (u32)(d < 4 ? d : 12 + d);  // +{0,1,2,3,16,17,18,19}
        x0[d] = a;                                // round 1: x0 = 0 + x1
        x1[d] = rotl_ab(a, 13) ^ a;
    }
#define TFR(R)                                             \
    _Pragma("unroll") for (int d = 0; d < 8; d++) {        \
        x0[d] += x1[d];                                    \
        x1[d] = rotl_ab(x1[d], R) ^ x0[d];                 \
    }
#define TFRI(R, A, B)                                      \
    _Pragma("unroll") for (int d = 0; d < 8; d++) {        \
        x1[d] += (B);                                      \
        x0[d] += (A) + x1[d];   /* v_add3_u32 */           \
        x1[d] = rotl_ab(x1[d], R) ^ x0[d];                 \
    }
    TFR(15) TFR(26) TFR(6)
    TFRI(17, K1, K2 + 1u) TFR(29) TFR(16) TFR(24)
    TFRI(13, K2, 2u)      TFR(15) TFR(26) TFR(6)
    TFRI(17, 0u, K1 + 3u) TFR(29) TFR(16) TFR(24)
    TFRI(13, K1, K2 + 4u) TFR(15) TFR(26) TFR(6)
#undef TFR
#undef TFRI
#pragma unroll
    for (int d = 0; d < 8; d++) {
        u32 bits = (x0[d] + K2) ^ (x1[d] + 5u);  // final inject folded
        // (bits>>9)|0x40000000 in ONE v_alignbit: ({0x80,bits}>>9)
        u32 vb = __builtin_amdgcn_alignbit(0x80u, bits, 9);
        float v2 = __uint_as_float(vb);  // 2+2f in [2,4)
        float u = v2 - 3.0f;             // exact 2f-1 (Sterbenz)
        float t = fmaf(-u, u, 1.0f);     // exact 1-u^2 (single rounding)
        float L2 = __log2f(t);           // v_log_f32; -inf at u=-1 ok (clamped)
        L2 = fmaxf(L2, -7.2134752f);     // w = -ln t <= 5  (5/ln2)
        float z = fmaf(L2, -0.69314718f, -2.5f);  // w - 2.5 in [-2.5, 2.5]
        float p = 2.81022636e-08f;
        p = fmaf(p, z, 3.43273939e-07f);
        p = fmaf(p, z, -3.5233877e-06f);
        p = fmaf(p, z, -4.39150654e-06f);
        p = fmaf(p, z, 0.00021858087f);
        p = fmaf(p, z, -0.00125372503f);
        p = fmaf(p, z, -0.00417768164f);
        p = fmaf(p, z, 0.246640727f);
        p = fmaf(p, z, 1.50140941f);
        pu[d] = p * u;  // erfinv(u); caller folds 0.05*sqrt(2)*log2e into fma
    }
}

// ---------------- absmax over the 4 f32 tensors (u32 bit compare, sign stripped)
__global__ __launch_bounds__(256) void absmax_k(const float* __restrict__ h,
                                                const float* __restrict__ wq,
                                                const float* __restrict__ wk,
                                                const float* __restrict__ wv,
                                                u32* __restrict__ slots) {
    int t = blockIdx.y;
    const float* src = (t == 0) ? h : (t == 1) ? wq : (t == 2) ? wk : wv;
    int n4 = ((t == 0) ? 4096 * 1024 : 1024 * 1024) / 4;
    u32 mx = 0;
    int tid = threadIdx.x;
    for (int i = blockIdx.x * blockDim.x + tid; i < n4; i += gridDim.x * blockDim.x) {
        uint4 v = ((const uint4*)src)[i];
        mx = max(mx, v.x & 0x7FFFFFFFu);
        mx = max(mx, v.y & 0x7FFFFFFFu);
        mx = max(mx, v.z & 0x7FFFFFFFu);
        mx = max(mx, v.w & 0x7FFFFFFFu);
    }
    __shared__ u32 red[256];
    red[tid] = mx;
    __syncthreads();
    for (int s = 128; s > 0; s >>= 1) {
        if (tid < s) red[tid] = max(red[tid], red[tid + s]);
        __syncthreads();
    }
    if (tid == 0) atomicMax(&slots[t], red[0]);
}

// ---------------- merged pre-quantize: y=0 hidden (8-bit, + raw bf16 copy),
// y=1..3 weights (4-bit)
__global__ __launch_bounds__(256) void prequant_all(const float* __restrict__ hidden,
                                                    const float* __restrict__ wq,
                                                    const float* __restrict__ wk,
                                                    const float* __restrict__ wv,
                                                    u16* __restrict__ hq,
                                                    u16* __restrict__ hbf,
                                                    u16* __restrict__ wqi,
                                                    u16* __restrict__ wki,
                                                    u16* __restrict__ wvi,
                                                    const u32* __restrict__ slots) {
    int y = blockIdx.y;
    const float* src = (y == 0) ? hidden : (y == 1) ? wq : (y == 2) ? wk : wv;
    u16* dqi = (y == 0) ? hq : (y == 1) ? wqi : (y == 2) ? wki : wvi;
    u16* draw = (y == 0) ? hbf : nullptr;
    float qmax = (y == 0) ? 127.0f : 7.0f;
    int n8 = ((y == 0) ? 4096 * 1024 : 1024 * 1024) / 8;

    float amax = fmaxf(__uint_as_float(slots[y]), 1e-8f);
    float scale = amax / qmax;  // IEEE f32, matches np
    for (int i = blockIdx.x * blockDim.x + threadIdx.x; i < n8; i += gridDim.x * blockDim.x) {
        float4 a = ((const float4*)src)[2 * i];
        float4 b = ((const float4*)src)[2 * i + 1];
        float x[8] = {a.x, a.y, a.z, a.w, b.x, b.y, b.z, b.w};
        u16 qi[8], rw[8];
#pragma unroll
        for (int j = 0; j < 8; j++) {
            float q = fminf(fmaxf(rintf(x[j] / scale), -qmax), qmax);  // IEEE div + half-even
            qi[j] = (u16)f2bfbits_exact(q);
            rw[j] = (u16)f2bfbits(x[j]);
        }
        *(uint4*)(dqi + 8 * (size_t)i) = *(const uint4*)qi;
        if (draw) *(uint4*)(draw + 8 * (size_t)i) = *(const uint4*)rw;
    }
}

// ---------------- merged projection GEMMs, 128x128 tile, m97-pattern staging
// (global_load_lds width=16 into linear LDS). z=0 Q, z=1 K, z=2 V^T.
__global__ __launch_bounds__(256, 2) void qkv_gemm_all(const u16* __restrict__ hq,
                                                       const u16* __restrict__ hbf,
                                                       const u16* __restrict__ wqi,
                                                       const u16* __restrict__ wki,
                                                       const u16* __restrict__ wvi,
                                                       const u32* __restrict__ slots,
                                                       u16* __restrict__ Qb,
                                                       u16* __restrict__ Kb,
                                                       u16* __restrict__ Vtb) {
    __shared__ __align__(16) u16 As[128 * 32];
    __shared__ __align__(16) u16 Bs[128 * 32];
    int z = blockIdx.z;
    const u16* A  = (z < 2) ? hq : hbf;
    const u16* Bw = (z == 0) ? wqi : (z == 1) ? wki : wvi;
    u16* outp     = (z == 0) ? Qb : (z == 1) ? Kb : Vtb;
    int transOut = (z == 2);
    float s_a = fmaxf(__uint_as_float(slots[0]), 1e-8f) / 127.0f;
    float s_w = fmaxf(__uint_as_float(slots[z + 1]), 1e-8f) / 7.0f;
    float oscale = (z < 2) ? (s_a * s_w) : s_w;

    int tid = threadIdx.x;
    int mbase = blockIdx.x * 128, nbase = blockIdx.y * 128;
    int lane = tid & 63, w = tid >> 6;
    int wv_m = w & 1, wv_n = w >> 1;
    int quad = lane >> 4, l16 = lane & 15;

    // staging addresses: wave w covers tile rows [32w, 32w+32)
    int srow = lane >> 2, scol = (lane & 3) * 8;
    const u16* ag0 = A + (size_t)(mbase + w * 32 + srow) * 1024 + scol;
    const u16* ag1 = A + (size_t)(mbase + w * 32 + 16 + srow) * 1024 + scol;
    const u16* bg0 = Bw + (size_t)(nbase + w * 32 + srow) * 1024 + scol;
    const u16* bg1 = Bw + (size_t)(nbase + w * 32 + 16 + srow) * 1024 + scol;
    u16* al0 = As + w * 1024;         // LDS block 2w   (elems; 1KB blocks)
    u16* al1 = As + w * 1024 + 512;   // LDS block 2w+1
    u16* bl0 = Bs + w * 1024;
    u16* bl1 = Bs + w * 1024 + 512;

    f32x4 acc[4][4];
#pragma unroll
    for (int i = 0; i < 4; i++)
#pragma unroll
        for (int j = 0; j < 4; j++) acc[i][j] = (f32x4){0.f, 0.f, 0.f, 0.f};

    for (int k0 = 0; k0 < 1024; k0 += 32) {
        __syncthreads();  // prev iteration's ds_reads complete before overwrite
        GLOAD_LDS16(ag0 + k0, al0);
        GLOAD_LDS16(ag1 + k0, al1);
        GLOAD_LDS16(bg0 + k0, bl0);
        GLOAD_LDS16(bg1 + k0, bl1);
        __syncthreads();  // compiler drains vmcnt before s_barrier

        bf16x8 af[4], bfr[4];
#pragma unroll
        for (int mt = 0; mt < 4; mt++)
            af[mt] = *(const bf16x8*)(As + (wv_m * 64 + mt * 16 + l16) * 32 + quad * 8);
#pragma unroll
        for (int nt = 0; nt < 4; nt++)
            bfr[nt] = *(const bf16x8*)(Bs + (wv_n * 64 + nt * 16 + l16) * 32 + quad * 8);
#pragma unroll
        for (int mt = 0; mt < 4; mt++)
#pragma unroll
            for (int nt = 0; nt < 4; nt++)
                acc[mt][nt] = MFMA16(af[mt], bfr[nt], acc[mt][nt]);
    }

#pragma unroll
    for (int mt = 0; mt < 4; mt++)
#pragma unroll
        for (int nt = 0; nt < 4; nt++)
#pragma unroll
            for (int r = 0; r < 4; r++) {
                float val = acc[mt][nt][r] * oscale;
                int m = mbase + wv_m * 64 + mt * 16 + quad * 4 + r;  // token
                int o = nbase + wv_n * 64 + nt * 16 + l16;           // out-feature
                int b = m >> 10, s = m & 1023;
                int hh = o >> 6, dh = o & 63;
                size_t off = transOut ? (((size_t)(b * 16 + hh) * 64 + dh) * 1024 + s)
                                      : (((size_t)(b * 16 + hh) * 1024 + s) * 64 + dh);
                outp[off] = (u16)f2bfbits(val);
            }
}

// ---------------- flash attention, SWAPPED-S / lane-local-P, NO SPLIT-K.
// R8: 128-thread (2-wave) blocks, grid (32,16,4) = 2048 blocks. R7's attn
// regression was residency granularity (1024 coarse blocks = one generation
// at 4/CU, occupancy 44->31): 2048 finer blocks restore R5's scheduling
// slack while KEEPING the combine-free structure (WRITE 16.4MB, no partial
// buffers). LDS 16KB (mask back to global reads, R4-proven) -> 8 blocks/CU.
// Each block: full 1024-step K-loop for 32 q-rows (2 waves x 16).
__global__ __launch_bounds__(128, 4) void attn_kernel(const u16* __restrict__ Q,
                                                      const u16* __restrict__ K,
                                                      const u16* __restrict__ Vt,
                                                      const float* __restrict__ mask,
                                                      float* __restrict__ outp) {
    __shared__ __align__(16) u16 Ks[2][32 * 64];   // [buf][k-row][d]   4KB each
    __shared__ __align__(16) u16 Vs[2][64 * 32];   // [buf][d][k-col]   4KB each

    int qt = blockIdx.x, h = blockIdx.y;
    int b = blockIdx.z;
    int bh = b * 16 + h;
    int tid = threadIdx.x, wv = tid >> 6, lane = tid & 63;
    int quad = lane >> 4, l16 = lane & 15;
    int q0 = qt * 32 + wv * 16;

    const float IL2 = 1.4426950408889634f;   // log2(e)
    const float C_S = 0.18033688011112042f;  // 0.125 * log2e
    const float C_N = 0.10201394645f;        // 0.05*sqrt(2) * log2e

    const float* maskb = mask + b * 1024;

    const u16* Qb = Q + (size_t)bh * 1024 * 64;
    const u16* Kb = K + (size_t)bh * 1024 * 64;
    const u16* Vb = Vt + (size_t)bh * 64 * 1024;  // row stride 1024 (seq)

    bf16x8 aq0 = *(const bf16x8*)(Qb + (q0 + l16) * 64 + quad * 8);
    bf16x8 aq1 = *(const bf16x8*)(Qb + (q0 + l16) * 64 + 32 + quad * 8);

    union { u32 u[4]; bf16x8 v; } ones;
#pragma unroll
    for (int i = 0; i < 4; i++) ones.u[i] = 0x3F803F80u;  // bf16 1.0 x8

    f32x4 oacc[4];
#pragma unroll
    for (int i = 0; i < 4; i++) oacc[i] = (f32x4){0.f, 0.f, 0.f, 0.f};
    f32x4 lacc = (f32x4){0.f, 0.f, 0.f, 0.f};

    // noise idx = (bh*1024 + q)*1024 + k, q = q0+l16 (lane-local),
    // k = kk + 4*quad + {0..3, 16..19}. +42 = threefry key pre-add.
    u32 tbase = ((u32)(bh * 1024 + q0 + l16)) * 1024u + (u32)(4 * quad) + 42u;

    // cooperative staging, 2 waves: wave wv stages K rows [16wv,16wv+16) and
    // V d-rows [32wv,32wv+32) per phase — 4 GLOAD_LDS16/wave/phase (2 K, 2 V).
    // HW writes LDS at (uniform base + lane*16B); source per-lane.
    const u16* kgsrc = Kb + (size_t)(wv * 16 + (lane >> 3)) * 64 + (lane & 7) * 8;
    const u16* vgsrc = Vb + (size_t)(wv * 32 + (lane >> 2)) * 1024 + (lane & 3) * 8;
    u16* kdst0 = &Ks[0][wv * 1024];   // 16 rows x 64 = 1024 elems (2 x 1KB)
    u16* kdst1 = &Ks[1][wv * 1024];
    u16* vdst0 = &Vs[0][wv * 1024];   // 32 d-rows x 32 = 1024 elems (2 x 1KB)
    u16* vdst1 = &Vs[1][wv * 1024];

    // prologue: stage kk=0 into buf 0
    GLOAD_LDS16(kgsrc, kdst0);
    GLOAD_LDS16(kgsrc + 8 * 64, kdst0 + 512);
    GLOAD_LDS16(vgsrc, vdst0);
    GLOAD_LDS16(vgsrc + 16 * 1024, vdst0 + 512);
    __syncthreads();

    for (int kk = 0; kk < 1024; kk += 32) {
        int cur = (kk >> 5) & 1;
        // issue next tile's stage first: lands during this phase's threefry
        if (kk + 32 < 1024) {
            const u16* kg = kgsrc + (kk + 32) * 64;
            const u16* vg = vgsrc + (kk + 32);
            u16* kd = cur ? kdst0 : kdst1;
            u16* vd = cur ? vdst0 : vdst1;
            GLOAD_LDS16(kg, kd);
            GLOAD_LDS16(kg + 8 * 64, kd + 512);
            GLOAD_LDS16(vg, vd);
            GLOAD_LDS16(vg + 16 * 1024, vd + 512);
        }
        const u16* Kc = cur ? Ks[1] : Ks[0];
        const u16* Vc = cur ? Vs[1] : Vs[0];

        // mask straight from global (quad-uniform f32x4, L1-broadcast)
        f32x4 mk4 = *(const f32x4*)(maskb + kk + 4 * quad);
        f32x4 mh4 = *(const f32x4*)(maskb + kk + 16 + 4 * quad);
        mk4 = mk4 * IL2;
        mh4 = mh4 * IL2;

        float pu[8];
        noise_pu8(tbase + (u32)kk, pu);

        // K frags from LDS (A-operand of swapped S^T = K Q^T)
        bf16x8 bk0 = *(const bf16x8*)(Kc + l16 * 64 + quad * 8);
        bf16x8 bk1 = *(const bf16x8*)(Kc + l16 * 64 + 32 + quad * 8);
        bf16x8 bk2 = *(const bf16x8*)(Kc + (16 + l16) * 64 + quad * 8);
        bf16x8 bk3 = *(const bf16x8*)(Kc + (16 + l16) * 64 + 32 + quad * 8);

        f32x4 s0 = (f32x4){0.f, 0.f, 0.f, 0.f};
        f32x4 s1 = (f32x4){0.f, 0.f, 0.f, 0.f};
        s0 = MFMA16(bk0, aq0, s0);
        s0 = MFMA16(bk1, aq1, s0);
        s1 = MFMA16(bk2, aq0, s1);
        s1 = MFMA16(bk3, aq1, s1);

        float e[8];
#pragma unroll
        for (int r = 0; r < 4; r++) {
            e[r]     = exp2_fast(fmaf(pu[r],     C_N, fmaf(s0[r], C_S, mk4[r])));
            e[4 + r] = exp2_fast(fmaf(pu[4 + r], C_N, fmaf(s1[r], C_S, mh4[r])));
        }
        union { u32 u[4]; bf16x8 v; } pf;
        pf.u[0] = pack_bf16x2(e[0], e[1]);
        pf.u[1] = pack_bf16x2(e[2], e[3]);
        pf.u[2] = pack_bf16x2(e[4], e[5]);
        pf.u[3] = pack_bf16x2(e[6], e[7]);

        // V frags from LDS, slot->k mapping matches P layout; O += P V
#pragma unroll
        for (int nt = 0; nt < 4; nt++) {
            bf16x4 vlo = *(const bf16x4*)(Vc + (nt * 16 + l16) * 32 + quad * 4);
            bf16x4 vhi = *(const bf16x4*)(Vc + (nt * 16 + l16) * 32 + 16 + quad * 4);
            bf16x8 vf = __builtin_shufflevector(vlo, vhi, 0, 1, 2, 3, 4, 5, 6, 7);
            oacc[nt] = MFMA16(pf.v, vf, oacc[nt]);
        }
        // row-sum l via ones-MFMA: D[row=q][*] = sum_k P
        lacc = MFMA16(pf.v, ones.v, lacc);

        __syncthreads();  // next-tile stage landed; all reads of buf done
    }

    // ---- epilogue: normalize in-register and write the final output directly.
#pragma unroll
    for (int r = 0; r < 4; r++) {
        float linv = 1.0f / lacc[r];
        int q = q0 + quad * 4 + r;
        float* orow = outp + ((size_t)(b * 1024 + q)) * 1024 + h * 64;
#pragma unroll
        for (int nt = 0; nt < 4; nt++)
            orow[nt * 16 + l16] = oacc[nt][r] * linv;
    }
}

extern "C" void kernel_launch(void* const* d_in, const int* in_sizes, int n_in,
                              void* d_out, int out_size, void* d_ws, size_t ws_size,
                              hipStream_t stream) {
    (void)in_sizes; (void)n_in; (void)out_size; (void)ws_size;
    const float* hidden = (const float*)d_in[0];
    const float* maskp  = (const float*)d_in[1];
    const float* Wq     = (const float*)d_in[2];
    const float* Wk     = (const float*)d_in[3];
    const float* Wv     = (const float*)d_in[4];
    float* outp = (float*)d_out;  // reference output dtype is float32

    char* ws = (char*)d_ws;
    u32* slots = (u32*)ws;                         // 4 x u32 (f32 bits of absmax)
    u16* hq  = (u16*)(ws + 256);                   // [4096][1024] int8 vals as bf16 (8 MB)
    u16* hbf = hq + 4096 * 1024;                   // [4096][1024] raw bf16 (8 MB)
    u16* wqi = hbf + 4096 * 1024;                  // [1024][1024] int4 vals as bf16 (2 MB)
    u16* wki = wqi + 1024 * 1024;
    u16* wvi = wki + 1024 * 1024;
    u16* Qb  = wvi + 1024 * 1024;                  // [B,H,S,64] (8 MB)
    u16* Kb  = Qb + 4096 * 1024;                   // [B,H,S,64] (8 MB)
    u16* Vtb = Kb + 4096 * 1024;                   // [B,H,64,S] (8 MB)

    hipMemsetAsync(slots, 0, 16, stream);
    absmax_k<<<dim3(128, 4), 256, 0, stream>>>(hidden, Wq, Wk, Wv, slots);
    prequant_all<<<dim3(64, 4), 256, 0, stream>>>(hidden, Wq, Wk, Wv,
                                                  hq, hbf, wqi, wki, wvi, slots);
    qkv_gemm_all<<<dim3(32, 8, 3), 256, 0, stream>>>(hq, hbf, wqi, wki, wvi, slots,
                                                     Qb, Kb, Vtb);
    attn_kernel<<<dim3(32, 16, 4), 128, 0, stream>>>(Qb, Kb, Vtb, maskp, outp);
}

// Round 9
// 339.849 us; speedup vs baseline: 1.0480x; 1.0480x over previous
//
#include <hip/hip_runtime.h>
#include <hip/hip_bf16.h>

typedef unsigned short u16;
typedef unsigned int u32;
typedef __bf16 bf16x8 __attribute__((ext_vector_type(8)));
typedef __bf16 bf16x4 __attribute__((ext_vector_type(4)));
typedef float f32x4 __attribute__((ext_vector_type(4)));

#define MFMA16(a, b, c) __builtin_amdgcn_mfma_f32_16x16x32_bf16((a), (b), (c), 0, 0, 0)

// async global->LDS, 16B per lane, wave-uniform LDS base (HW: base + lane*16)
#define GLOAD_LDS16(gp, lp)                                        \
    __builtin_amdgcn_global_load_lds(                              \
        (const __attribute__((address_space(1))) void*)(gp),       \
        (__attribute__((address_space(3))) void*)(lp), 16, 0, 0)

// round-to-nearest-even f32 -> bf16 bits
static __device__ __forceinline__ u32 f2bfbits(float f) {
    union { float f; u32 u; } c; c.f = f;
    return (c.u + 0x7FFFu + ((c.u >> 16) & 1u)) >> 16;
}
// exact for small integers (|v| <= 255): low 16 mantissa bits are zero
static __device__ __forceinline__ u32 f2bfbits_exact(float f) {
    union { float f; u32 u; } c; c.f = f;
    return c.u >> 16;
}
// packed RNE f32x2 -> bf16x2
static __device__ __forceinline__ u32 pack_bf16x2(float lo, float hi) {
    float2 v; v.x = lo; v.y = hi;
    union { __hip_bfloat162 h; u32 u; } c;
    c.h = __float22bfloat162_rn(v);
    return c.u;  // low 16 = lo, high 16 = hi
}

// guaranteed single-instruction rotate: v_alignbit_b32(x,x,32-r) == rotl(x,r)
static __device__ __forceinline__ u32 rotl_ab(u32 x, int r) {
    return __builtin_amdgcn_alignbit(x, x, 32 - r);
}

// v_exp_f32 computes 2^x. Inline asm so we skip __expf's ln2 multiply (the
// constants upstream are pre-scaled by log2e). s_nop 1 covers the VALU-trans
// use hazard, which the scheduler cannot see inside opaque asm.
static __device__ __forceinline__ float exp2_fast(float x) {
    float r;
    asm("v_exp_f32 %0, %1\n\ts_nop 1" : "=v"(r) : "v"(x));
    return r;
}

// ---------------- batched JAX threefry2x32, key (0,42), 8 draws in lockstep.
// Partitionable mode (HW-verified): counter=(0,idx), bits=x0^x1.
// tk = base_idx + 42 (key pre-added); draw d uses idx offset {0,1,2,3,16,17,18,19}.
// Harness-verified bitstream (R0..R8 absmax identical). Scalar-tail form
// (R6's packed-pair variant regressed) + alignbit uniform-bits (R5-proven).
static __device__ __forceinline__ void noise_pu8(u32 tk, float* __restrict__ pu) {
    const u32 K1 = 42u, K2 = 0x1BD11BF0u;  // 0x1BD11BDA ^ 42
    u32 x0[8], x1[8];
#pragma unroll
    for (int d = 0; d < 8; d++) {
        u32 a = tk + (u32)(d < 4 ? d : 12 + d);  // +{0,1,2,3,16,17,18,19}
        x0[d] = a;                                // round 1: x0 = 0 + x1
        x1[d] = rotl_ab(a, 13) ^ a;
    }
#define TFR(R)                                             \
    _Pragma("unroll") for (int d = 0; d < 8; d++) {        \
        x0[d] += x1[d];                                    \
        x1[d] = rotl_ab(x1[d], R) ^ x0[d];                 \
    }
#define TFRI(R, A, B)                                      \
    _Pragma("unroll") for (int d = 0; d < 8; d++) {        \
        x1[d] += (B);                                      \
        x0[d] += (A) + x1[d];   /* v_add3_u32 */           \
        x1[d] = rotl_ab(x1[d], R) ^ x0[d];                 \
    }
    TFR(15) TFR(26) TFR(6)
    TFRI(17, K1, K2 + 1u) TFR(29) TFR(16) TFR(24)
    TFRI(13, K2, 2u)      TFR(15) TFR(26) TFR(6)
    TFRI(17, 0u, K1 + 3u) TFR(29) TFR(16) TFR(24)
    TFRI(13, K1, K2 + 4u) TFR(15) TFR(26) TFR(6)
#undef TFR
#undef TFRI
#pragma unroll
    for (int d = 0; d < 8; d++) {
        u32 bits = (x0[d] + K2) ^ (x1[d] + 5u);  // final inject folded
        // (bits>>9)|0x40000000 in ONE v_alignbit: ({0x80,bits}>>9)
        u32 vb = __builtin_amdgcn_alignbit(0x80u, bits, 9);
        float v2 = __uint_as_float(vb);  // 2+2f in [2,4)
        float u = v2 - 3.0f;             // exact 2f-1 (Sterbenz)
        float t = fmaf(-u, u, 1.0f);     // exact 1-u^2 (single rounding)
        float L2 = __log2f(t);           // v_log_f32; -inf at u=-1 ok (clamped)
        L2 = fmaxf(L2, -7.2134752f);     // w = -ln t <= 5  (5/ln2)
        float z = fmaf(L2, -0.69314718f, -2.5f);  // w - 2.5 in [-2.5, 2.5]
        float p = 2.81022636e-08f;
        p = fmaf(p, z, 3.43273939e-07f);
        p = fmaf(p, z, -3.5233877e-06f);
        p = fmaf(p, z, -4.39150654e-06f);
        p = fmaf(p, z, 0.00021858087f);
        p = fmaf(p, z, -0.00125372503f);
        p = fmaf(p, z, -0.00417768164f);
        p = fmaf(p, z, 0.246640727f);
        p = fmaf(p, z, 1.50140941f);
        pu[d] = p * u;  // erfinv(u); caller folds 0.05*sqrt(2)*log2e into fma
    }
}

// ---------------- absmax over the 4 f32 tensors (u32 bit compare, sign stripped)
__global__ __launch_bounds__(256) void absmax_k(const float* __restrict__ h,
                                                const float* __restrict__ wq,
                                                const float* __restrict__ wk,
                                                const float* __restrict__ wv,
                                                u32* __restrict__ slots) {
    int t = blockIdx.y;
    const float* src = (t == 0) ? h : (t == 1) ? wq : (t == 2) ? wk : wv;
    int n4 = ((t == 0) ? 4096 * 1024 : 1024 * 1024) / 4;
    u32 mx = 0;
    int tid = threadIdx.x;
    for (int i = blockIdx.x * blockDim.x + tid; i < n4; i += gridDim.x * blockDim.x) {
        uint4 v = ((const uint4*)src)[i];
        mx = max(mx, v.x & 0x7FFFFFFFu);
        mx = max(mx, v.y & 0x7FFFFFFFu);
        mx = max(mx, v.z & 0x7FFFFFFFu);
        mx = max(mx, v.w & 0x7FFFFFFFu);
    }
    __shared__ u32 red[256];
    red[tid] = mx;
    __syncthreads();
    for (int s = 128; s > 0; s >>= 1) {
        if (tid < s) red[tid] = max(red[tid], red[tid + s]);
        __syncthreads();
    }
    if (tid == 0) atomicMax(&slots[t], red[0]);
}

// ---------------- merged pre-quantize: y=0 hidden (8-bit, + raw bf16 copy),
// y=1..3 weights (4-bit)
__global__ __launch_bounds__(256) void prequant_all(const float* __restrict__ hidden,
                                                    const float* __restrict__ wq,
                                                    const float* __restrict__ wk,
                                                    const float* __restrict__ wv,
                                                    u16* __restrict__ hq,
                                                    u16* __restrict__ hbf,
                                                    u16* __restrict__ wqi,
                                                    u16* __restrict__ wki,
                                                    u16* __restrict__ wvi,
                                                    const u32* __restrict__ slots) {
    int y = blockIdx.y;
    const float* src = (y == 0) ? hidden : (y == 1) ? wq : (y == 2) ? wk : wv;
    u16* dqi = (y == 0) ? hq : (y == 1) ? wqi : (y == 2) ? wki : wvi;
    u16* draw = (y == 0) ? hbf : nullptr;
    float qmax = (y == 0) ? 127.0f : 7.0f;
    int n8 = ((y == 0) ? 4096 * 1024 : 1024 * 1024) / 8;

    float amax = fmaxf(__uint_as_float(slots[y]), 1e-8f);
    float scale = amax / qmax;  // IEEE f32, matches np
    for (int i = blockIdx.x * blockDim.x + threadIdx.x; i < n8; i += gridDim.x * blockDim.x) {
        float4 a = ((const float4*)src)[2 * i];
        float4 b = ((const float4*)src)[2 * i + 1];
        float x[8] = {a.x, a.y, a.z, a.w, b.x, b.y, b.z, b.w};
        u16 qi[8], rw[8];
#pragma unroll
        for (int j = 0; j < 8; j++) {
            float q = fminf(fmaxf(rintf(x[j] / scale), -qmax), qmax);  // IEEE div + half-even
            qi[j] = (u16)f2bfbits_exact(q);
            rw[j] = (u16)f2bfbits(x[j]);
        }
        *(uint4*)(dqi + 8 * (size_t)i) = *(const uint4*)qi;
        if (draw) *(uint4*)(draw + 8 * (size_t)i) = *(const uint4*)rw;
    }
}

// ---------------- merged projection GEMMs, 128x128 tile, m97-pattern staging
// (global_load_lds width=16 into linear LDS). z=0 Q, z=1 K, z=2 V^T.
__global__ __launch_bounds__(256, 2) void qkv_gemm_all(const u16* __restrict__ hq,
                                                       const u16* __restrict__ hbf,
                                                       const u16* __restrict__ wqi,
                                                       const u16* __restrict__ wki,
                                                       const u16* __restrict__ wvi,
                                                       const u32* __restrict__ slots,
                                                       u16* __restrict__ Qb,
                                                       u16* __restrict__ Kb,
                                                       u16* __restrict__ Vtb) {
    __shared__ __align__(16) u16 As[128 * 32];
    __shared__ __align__(16) u16 Bs[128 * 32];
    int z = blockIdx.z;
    const u16* A  = (z < 2) ? hq : hbf;
    const u16* Bw = (z == 0) ? wqi : (z == 1) ? wki : wvi;
    u16* outp     = (z == 0) ? Qb : (z == 1) ? Kb : Vtb;
    int transOut = (z == 2);
    float s_a = fmaxf(__uint_as_float(slots[0]), 1e-8f) / 127.0f;
    float s_w = fmaxf(__uint_as_float(slots[z + 1]), 1e-8f) / 7.0f;
    float oscale = (z < 2) ? (s_a * s_w) : s_w;

    int tid = threadIdx.x;
    int mbase = blockIdx.x * 128, nbase = blockIdx.y * 128;
    int lane = tid & 63, w = tid >> 6;
    int wv_m = w & 1, wv_n = w >> 1;
    int quad = lane >> 4, l16 = lane & 15;

    // staging addresses: wave w covers tile rows [32w, 32w+32)
    int srow = lane >> 2, scol = (lane & 3) * 8;
    const u16* ag0 = A + (size_t)(mbase + w * 32 + srow) * 1024 + scol;
    const u16* ag1 = A + (size_t)(mbase + w * 32 + 16 + srow) * 1024 + scol;
    const u16* bg0 = Bw + (size_t)(nbase + w * 32 + srow) * 1024 + scol;
    const u16* bg1 = Bw + (size_t)(nbase + w * 32 + 16 + srow) * 1024 + scol;
    u16* al0 = As + w * 1024;         // LDS block 2w   (elems; 1KB blocks)
    u16* al1 = As + w * 1024 + 512;   // LDS block 2w+1
    u16* bl0 = Bs + w * 1024;
    u16* bl1 = Bs + w * 1024 + 512;

    f32x4 acc[4][4];
#pragma unroll
    for (int i = 0; i < 4; i++)
#pragma unroll
        for (int j = 0; j < 4; j++) acc[i][j] = (f32x4){0.f, 0.f, 0.f, 0.f};

    for (int k0 = 0; k0 < 1024; k0 += 32) {
        __syncthreads();  // prev iteration's ds_reads complete before overwrite
        GLOAD_LDS16(ag0 + k0, al0);
        GLOAD_LDS16(ag1 + k0, al1);
        GLOAD_LDS16(bg0 + k0, bl0);
        GLOAD_LDS16(bg1 + k0, bl1);
        __syncthreads();  // compiler drains vmcnt before s_barrier

        bf16x8 af[4], bfr[4];
#pragma unroll
        for (int mt = 0; mt < 4; mt++)
            af[mt] = *(const bf16x8*)(As + (wv_m * 64 + mt * 16 + l16) * 32 + quad * 8);
#pragma unroll
        for (int nt = 0; nt < 4; nt++)
            bfr[nt] = *(const bf16x8*)(Bs + (wv_n * 64 + nt * 16 + l16) * 32 + quad * 8);
#pragma unroll
        for (int mt = 0; mt < 4; mt++)
#pragma unroll
            for (int nt = 0; nt < 4; nt++)
                acc[mt][nt] = MFMA16(af[mt], bfr[nt], acc[mt][nt]);
    }

#pragma unroll
    for (int mt = 0; mt < 4; mt++)
#pragma unroll
        for (int nt = 0; nt < 4; nt++)
#pragma unroll
            for (int r = 0; r < 4; r++) {
                float val = acc[mt][nt][r] * oscale;
                int m = mbase + wv_m * 64 + mt * 16 + quad * 4 + r;  // token
                int o = nbase + wv_n * 64 + nt * 16 + l16;           // out-feature
                int b = m >> 10, s = m & 1023;
                int hh = o >> 6, dh = o & 63;
                size_t off = transOut ? (((size_t)(b * 16 + hh) * 64 + dh) * 1024 + s)
                                      : (((size_t)(b * 16 + hh) * 1024 + s) * 64 + dh);
                outp[off] = (u16)f2bfbits(val);
            }
}

// ---------------- split-K flash attention, SWAPPED-S / lane-local-P.
// R9 = the R1 configuration EXACTLY (best measured: 211.9 us, occ 43.7,
// VALUBusy 97.5, VGPR 48): 4-wave blocks, split-K=2 (2048 blocks = TWO
// residency generations at 4 blocks/CU — the only shape that measured 44%
// occupancy), scattered per-lane K/V loads (R5 proved LDS staging buys
// nothing), LDS mask premul, scalar lsum + shfl epilogue (R2's ones-MFMA
// variant measured SLOWER). Fixed-reference softmax (M=0) => partials
// combine ADDITIVELY in combine_k.
__global__ __launch_bounds__(256, 4) void attn_kernel(const u16* __restrict__ Q,
                                                      const u16* __restrict__ K,
                                                      const u16* __restrict__ Vt,
                                                      const float* __restrict__ mask,
                                                      float* __restrict__ O0,
                                                      float* __restrict__ O1,
                                                      float* __restrict__ l0,
                                                      float* __restrict__ l1) {
    __shared__ float msk[512];  // mask * log2e for this split's k-range
    int qt = blockIdx.x, h = blockIdx.y;
    int b = blockIdx.z & 3, split = blockIdx.z >> 2;
    int bh = b * 16 + h;
    int tid = threadIdx.x, wv = tid >> 6, lane = tid & 63;
    int quad = lane >> 4, l16 = lane & 15;
    int q0 = qt * 64 + wv * 16;
    int ks0 = split * 512;

    const float IL2 = 1.4426950408889634f;  // log2(e)
    const float* maskb = mask + b * 1024 + ks0;
    msk[tid] = maskb[tid] * IL2;
    msk[tid + 256] = maskb[tid + 256] * IL2;
    __syncthreads();

    float* Obuf = split ? O1 : O0;
    float* lbuf = split ? l1 : l0;
    const u16* Qb = Q + (size_t)bh * 1024 * 64;
    const u16* Kb = K + (size_t)bh * 1024 * 64;
    const u16* Vb = Vt + (size_t)bh * 64 * 1024 + ks0;  // row stride 1024 (seq)

    bf16x8 aq0 = *(const bf16x8*)(Qb + (q0 + l16) * 64 + quad * 8);
    bf16x8 aq1 = *(const bf16x8*)(Qb + (q0 + l16) * 64 + 32 + quad * 8);

    f32x4 oacc[4];
#pragma unroll
    for (int i = 0; i < 4; i++) oacc[i] = (f32x4){0.f, 0.f, 0.f, 0.f};
    float lsum = 0.f;

    // noise idx = (bh*1024 + q)*1024 + k, q = q0+l16 (lane-local),
    // k = ks0 + kk + 4*quad + {0..3, 16..19}. +42 = threefry key pre-add.
    u32 tbase = ((u32)(bh * 1024 + q0 + l16)) * 1024u + (u32)ks0 + (u32)(4 * quad) + 42u;

    const float C_S = 0.18033688011112042f;  // 0.125 * log2e
    const float C_N = 0.10201394645f;        // 0.05*sqrt(2) * log2e

    for (int kk = 0; kk < 512; kk += 32) {
        // ---- loads first: latency hides under the ~550-instr threefry block
        const u16* Kt = Kb + (size_t)(ks0 + kk) * 64;
        bf16x8 bk0 = *(const bf16x8*)(Kt + l16 * 64 + quad * 8);
        bf16x8 bk1 = *(const bf16x8*)(Kt + l16 * 64 + 32 + quad * 8);
        bf16x8 bk2 = *(const bf16x8*)(Kt + (16 + l16) * 64 + quad * 8);
        bf16x8 bk3 = *(const bf16x8*)(Kt + (16 + l16) * 64 + 32 + quad * 8);

        const u16* Vk = Vb + kk + 4 * quad;
        bf16x4 vlo[4], vhi[4];
#pragma unroll
        for (int nt = 0; nt < 4; nt++) {
            vlo[nt] = *(const bf16x4*)(Vk + (nt * 16 + l16) * 1024);
            vhi[nt] = *(const bf16x4*)(Vk + (nt * 16 + l16) * 1024 + 16);
        }

        // mask (pre-scaled by log2e); broadcast within each quad -> conflict-free
        int mb = kk + 4 * quad;
        float mk[4], mh[4];
#pragma unroll
        for (int r = 0; r < 4; r++) { mk[r] = msk[mb + r]; mh[r] = msk[mb + 16 + r]; }

        // ---- 8 noise draws, batched (independent of all loads/MFMAs)
        float pu[8];
        noise_pu8(tbase + (u32)kk, pu);

        // ---- S^T = K Q^T for 32 k-rows x 16 q-cols (swapped operands)
        f32x4 s0 = (f32x4){0.f, 0.f, 0.f, 0.f};
        f32x4 s1 = (f32x4){0.f, 0.f, 0.f, 0.f};
        s0 = MFMA16(bk0, aq0, s0);
        s0 = MFMA16(bk1, aq1, s0);
        s1 = MFMA16(bk2, aq0, s1);
        s1 = MFMA16(bk3, aq1, s1);

        // ---- softmax numerator, all in-lane: e = 2^(s*C_S + pu*C_N + mk2)
        float e[8];
#pragma unroll
        for (int r = 0; r < 4; r++) {
            e[r]     = exp2_fast(fmaf(pu[r],     C_N, fmaf(s0[r], C_S, mk[r])));
            e[4 + r] = exp2_fast(fmaf(pu[4 + r], C_N, fmaf(s1[r], C_S, mh[r])));
        }
        lsum += ((e[0] + e[1]) + (e[2] + e[3])) + ((e[4] + e[5]) + (e[6] + e[7]));

        // ---- pack P into the PV A-fragment (slot j<4: k=4q+j, j>=4: k=16+4q+j-4)
        union { u32 u[4]; bf16x8 v; } pf;
        pf.u[0] = pack_bf16x2(e[0], e[1]);
        pf.u[1] = pack_bf16x2(e[2], e[3]);
        pf.u[2] = pack_bf16x2(e[4], e[5]);
        pf.u[3] = pack_bf16x2(e[6], e[7]);

        // ---- O += P V, V B-fragment built with the SAME slot->k mapping
#pragma unroll
        for (int nt = 0; nt < 4; nt++) {
            bf16x8 vf = __builtin_shufflevector(vlo[nt], vhi[nt], 0, 1, 2, 3, 4, 5, 6, 7);
            oacc[nt] = MFMA16(pf.v, vf, oacc[nt]);
        }
    }

    // ---- epilogue: write UNNORMALIZED O and per-row l sums
    float l = lsum;
    l += __shfl_xor(l, 16);
    l += __shfl_xor(l, 32);
    if (lane < 16) lbuf[bh * 1024 + q0 + lane] = l;  // quad 0 lanes hold q=q0+l16
#pragma unroll
    for (int nt = 0; nt < 4; nt++) {
#pragma unroll
        for (int r = 0; r < 4; r++) {
            int q = q0 + quad * 4 + r;
            int dh = nt * 16 + l16;
            Obuf[((size_t)(b * 1024 + q)) * 1024 + h * 64 + dh] = oacc[nt][r];
        }
    }
}

// ---------------- combine: out = (O0 + O1) / (l0 + l1), 1 float4/thread
__global__ __launch_bounds__(256) void combine_k(float* __restrict__ outp,
                                                 const float* __restrict__ O1,
                                                 const float* __restrict__ l0,
                                                 const float* __restrict__ l1) {
    int gid = blockIdx.x * 256 + threadIdx.x;  // 1,048,576 float4s
    int e = gid << 2;
    int bq = e >> 10;                 // b*1024 + q
    int h = (e & 1023) >> 6;
    int b = bq >> 10, q = bq & 1023;
    int lidx = ((b * 16 + h) << 10) + q;
    float linv = 1.0f / (l0[lidx] + l1[lidx]);
    float4 a = ((const float4*)outp)[gid];
    float4 c = ((const float4*)O1)[gid];
    float4 o;
    o.x = (a.x + c.x) * linv;
    o.y = (a.y + c.y) * linv;
    o.z = (a.z + c.z) * linv;
    o.w = (a.w + c.w) * linv;
    ((float4*)outp)[gid] = o;
}

extern "C" void kernel_launch(void* const* d_in, const int* in_sizes, int n_in,
                              void* d_out, int out_size, void* d_ws, size_t ws_size,
                              hipStream_t stream) {
    (void)in_sizes; (void)n_in; (void)out_size; (void)ws_size;
    const float* hidden = (const float*)d_in[0];
    const float* maskp  = (const float*)d_in[1];
    const float* Wq     = (const float*)d_in[2];
    const float* Wk     = (const float*)d_in[3];
    const float* Wv     = (const float*)d_in[4];
    float* outp = (float*)d_out;  // reference output dtype is float32

    char* ws = (char*)d_ws;
    u32* slots = (u32*)ws;                         // 4 x u32 (f32 bits of absmax)
    u16* hq  = (u16*)(ws + 256);                   // [4096][1024] int8 vals as bf16 (8 MB)
    u16* hbf = hq + 4096 * 1024;                   // [4096][1024] raw bf16 (8 MB)
    u16* wqi = hbf + 4096 * 1024;                  // [1024][1024] int4 vals as bf16 (2 MB)
    u16* wki = wqi + 1024 * 1024;
    u16* wvi = wki + 1024 * 1024;
    u16* Qb  = wvi + 1024 * 1024;                  // [B,H,S,64] (8 MB)
    u16* Kb  = Qb + 4096 * 1024;                   // [B,H,S,64] (8 MB)
    u16* Vtb = Kb + 4096 * 1024;                   // [B,H,64,S] (8 MB)

    // dead-after-GEMM regions reused by split-K attention:
    float* O1buf = (float*)hq;                     // 16 MB over hq+hbf
    float* l0buf = (float*)wqi;                    // 256 KB (B*H*S f32)
    float* l1buf = l0buf + 4 * 16 * 1024;          // next 256 KB

    hipMemsetAsync(slots, 0, 16, stream);
    absmax_k<<<dim3(128, 4), 256, 0, stream>>>(hidden, Wq, Wk, Wv, slots);
    prequant_all<<<dim3(64, 4), 256, 0, stream>>>(hidden, Wq, Wk, Wv,
                                                  hq, hbf, wqi, wki, wvi, slots);
    qkv_gemm_all<<<dim3(32, 8, 3), 256, 0, stream>>>(hq, hbf, wqi, wki, wvi, slots,
                                                     Qb, Kb, Vtb);
    attn_kernel<<<dim3(16, 16, 8), 256, 0, stream>>>(Qb, Kb, Vtb, maskp,
                                                     outp, O1buf, l0buf, l1buf);
    combine_k<<<dim3(4096), 256, 0, stream>>>(outp, O1buf, l0buf, l1buf);
}